// Round 7
// baseline (1689.751 us; speedup 1.0000x reference)
//
#include <hip/hip_runtime.h>

#define B_ 16
#define N_ 4096
#define CIN_ 64
#define COUT_ 128
#define K_ 16
#define M_ 1024

typedef float f32x2 __attribute__((ext_vector_type(2)));
typedef unsigned long long u64;

#define DPPF(m, ctrl)                                                          \
  m = fmaxf(m, __int_as_float(__builtin_amdgcn_update_dpp(                     \
                  0, __float_as_int(m), ctrl, 0xF, 0xF, true)))
#define DPPI(e, ctrl)                                                          \
  e = max(e, __builtin_amdgcn_update_dpp(0, e, ctrl, 0xF, 0xF, true))

__device__ __forceinline__ unsigned mono32(float d) {
  unsigned u = __float_as_uint(d);
  return u ^ (unsigned)(((int)u >> 31) | 0x80000000);
}
__device__ __forceinline__ unsigned short f2bf(float x) {
  const unsigned u = __float_as_uint(x);
  return (unsigned short)((u + 0x7FFF + ((u >> 16) & 1)) >> 16);  // RNE
}

// ctrl layout (zeroed by memset): [0..2048) stats sums; [2048..2112) prog[16]
// Roles: [0,16) FPS | [16,528) linear+stats | [528,..) kNN splits (qt-major).
__global__ __launch_bounds__(512) void mega_kernel(
    const float* __restrict__ pos, const float* __restrict__ features,
    const float* __restrict__ W, const float* __restrict__ bias,
    int* __restrict__ fps_idx, unsigned short* __restrict__ h,
    float* __restrict__ ctrl, u64* __restrict__ cand, int S) {
  __shared__ __align__(16) char smem[84 * 1024];
  const int id = blockIdx.x;
  const int t = threadIdx.x;
  float* stats = ctrl;
  int* prog = (int*)(ctrl + 512);

  if (id < B_) {
    // ---- FPS: barrier-free, register-resident points, coord-carrying reduce
    const int b = id;
    volatile u64* slots = (volatile u64*)smem;  // [2 parity][4 wave][4 u64]
    const float* pb = pos + (size_t)b * N_ * 3;
    if (t < 32) ((u64*)smem)[t] = 0;  // tag 0 never matches step>=1
    __syncthreads();
    if (t >= 256) return;
    f32x2 px[8], py[8], pz[8], md[8];
#pragma unroll
    for (int j = 0; j < 8; ++j) {
      const float* r0 = pb + (size_t)(t + 512 * j) * 3;
      const float* r1 = pb + (size_t)(t + 512 * j + 256) * 3;
      px[j] = (f32x2){r0[0], r1[0]};
      py[j] = (f32x2){r0[1], r1[1]};
      pz[j] = (f32x2){r0[2], r1[2]};
      md[j] = (f32x2){1e10f, 1e10f};
    }
    if (t == 0) fps_idx[b * M_] = 0;
    const int wv = t >> 6, ln = t & 63;
    const int e0 = 65535 - t;  // enc = 65535 - idx; idx = t + 256*(2j+h)
    float lx = pb[0], ly = pb[1], lz = pb[2];
    for (int step = 1; step < M_; ++step) {
      const f32x2 vlx = {lx, lx}, vly = {ly, ly}, vlz = {lz, lz};
      float bestd = -1.0f;
      int be = 0;
      {
#pragma clang fp contract(off)
#pragma unroll
        for (int j = 0; j < 8; ++j) {
          const f32x2 dx = px[j] - vlx;
          const f32x2 dy = py[j] - vly;
          const f32x2 dz = pz[j] - vlz;
          const f32x2 s1 = dx * dx;
          const f32x2 s2 = dy * dy;
          const f32x2 s3 = dz * dz;
          const f32x2 d = (s1 + s2) + s3;  // exact reference order
          f32x2 nd;
          nd.x = fminf(md[j].x, d.x);
          nd.y = fminf(md[j].y, d.y);
          md[j] = nd;
          if (nd.x > bestd) { bestd = nd.x; be = e0 - (j << 9); }
          if (nd.y > bestd) { bestd = nd.y; be = e0 - (j << 9) - 256; }
        }
      }
      // own best candidate's coords via register tree (off critical path)
      const unsigned u = (unsigned)(65535 - be - t) >> 8;  // 2j+h
      const int b0 = u & 2, b1 = u & 4, b2 = u & 8, hh = u & 1;
      f32x2 xs, ys, zs;
      {
        const f32x2 x01 = b0 ? px[1] : px[0], x23 = b0 ? px[3] : px[2];
        const f32x2 x45 = b0 ? px[5] : px[4], x67 = b0 ? px[7] : px[6];
        const f32x2 x03 = b1 ? x23 : x01, x47 = b1 ? x67 : x45;
        xs = b2 ? x47 : x03;
        const f32x2 y01 = b0 ? py[1] : py[0], y23 = b0 ? py[3] : py[2];
        const f32x2 y45 = b0 ? py[5] : py[4], y67 = b0 ? py[7] : py[6];
        const f32x2 y03 = b1 ? y23 : y01, y47 = b1 ? y67 : y45;
        ys = b2 ? y47 : y03;
        const f32x2 z01 = b0 ? pz[1] : pz[0], z23 = b0 ? pz[3] : pz[2];
        const f32x2 z45 = b0 ? pz[5] : pz[4], z67 = b0 ? pz[7] : pz[6];
        const f32x2 z03 = b1 ? z23 : z01, z47 = b1 ? z67 : z45;
        zs = b2 ? z47 : z03;
      }
      const float wx = hh ? xs.y : xs.x;
      const float wy = hh ? ys.y : ys.x;
      const float wz = hh ? zs.y : zs.x;
      // wave reduce
      float m = bestd;
      DPPF(m, 0x111); DPPF(m, 0x112); DPPF(m, 0x114); DPPF(m, 0x118);
      DPPF(m, 0x142); DPPF(m, 0x143);
      const float wm =
          __int_as_float(__builtin_amdgcn_readlane(__float_as_int(m), 63));
      int enc = (bestd == wm) ? be : 0;
      DPPI(enc, 0x111); DPPI(enc, 0x112); DPPI(enc, 0x114); DPPI(enc, 0x118);
      DPPI(enc, 0x142); DPPI(enc, 0x143);
      const int wenc = __builtin_amdgcn_readlane(enc, 63);
      const unsigned tag = (unsigned)(step & 1023);
      volatile u64* sb = slots + (step & 1) * 16 + wv * 4;
      if (ln == 0)
        sb[0] = ((u64)__float_as_uint(wm) << 32) | ((u64)tag << 16) |
                (unsigned)wenc;
      if (be == wenc) {  // unique wave-winner lane publishes coords
        sb[1] = ((u64)__float_as_uint(wy) << 32) | __float_as_uint(wx);
        sb[2] = ((u64)tag << 32) | __float_as_uint(wz);
      }
      // tag-poll all 4 waves' slots (12 parallel ds_read_b64)
      volatile u64* base = slots + (step & 1) * 16;
      u64 T[4], XY[4], ZC[4];
      for (;;) {
        unsigned bad = 0;
#pragma unroll
        for (int w = 0; w < 4; ++w) {
          T[w] = base[w * 4 + 0];
          XY[w] = base[w * 4 + 1];
          ZC[w] = base[w * 4 + 2];
          bad |= (((unsigned)(T[w] >> 16)) & 1023u) ^ tag;
          bad |= ((unsigned)(ZC[w] >> 32)) ^ tag;
        }
        if (!bad) break;
      }
      // select max tuple + its coords (encs distinct -> strict order)
      const bool c01 = T[0] > T[1], c23 = T[2] > T[3];
      const u64 ta = c01 ? T[0] : T[1], xa = c01 ? XY[0] : XY[1],
                za = c01 ? ZC[0] : ZC[1];
      const u64 tb = c23 ? T[2] : T[3], xb = c23 ? XY[2] : XY[3],
                zb = c23 ? ZC[2] : ZC[3];
      const bool cab = ta > tb;
      const u64 rr = cab ? ta : tb, rxy = cab ? xa : xb, rzc = cab ? za : zb;
      lx = __uint_as_float((unsigned)rxy);
      ly = __uint_as_float((unsigned)(rxy >> 32));
      lz = __uint_as_float((unsigned)rzc);
      if (t == 0) {
        fps_idx[b * M_ + step] = 65535 - (int)(unsigned)(rr & 0xFFFFu);
        if ((step & 63) == 63)
          __hip_atomic_store(&prog[b], (step >> 6) + 1, __ATOMIC_RELEASE,
                             __HIP_MEMORY_SCOPE_AGENT);
      }
    }
    return;
  }

  if (id < B_ + 512) {
    // ---------------- linear (h bf16) + stats partials ----------------
    const int lid = id - B_;
    float* ls = (float*)smem;  // 256 floats
    for (int i = t; i < 256; i += 512) ls[i] = 0.f;
    __syncthreads();
    const int o4 = (t & 31) << 2;
    const int rl = t >> 5;
    const float4 bv = *(const float4*)(bias + o4);
    float4 s4 = {0, 0, 0, 0}, ss4 = {0, 0, 0, 0};
    for (int i = 0; i < 8; ++i) {
      const int r = lid * 128 + rl * 8 + i;
      const float4* fr = (const float4*)(features + (size_t)r * CIN_);
      float4 acc = bv;
#pragma unroll
      for (int c4 = 0; c4 < 16; ++c4) {
        const float4 fv = fr[c4];
        const float* wr = W + (size_t)(c4 * 4) * COUT_ + o4;
        const float4 w0 = *(const float4*)(wr);
        const float4 w1 = *(const float4*)(wr + COUT_);
        const float4 w2 = *(const float4*)(wr + 2 * COUT_);
        const float4 w3 = *(const float4*)(wr + 3 * COUT_);
        acc.x = fmaf(fv.x, w0.x, acc.x); acc.y = fmaf(fv.x, w0.y, acc.y);
        acc.z = fmaf(fv.x, w0.z, acc.z); acc.w = fmaf(fv.x, w0.w, acc.w);
        acc.x = fmaf(fv.y, w1.x, acc.x); acc.y = fmaf(fv.y, w1.y, acc.y);
        acc.z = fmaf(fv.y, w1.z, acc.z); acc.w = fmaf(fv.y, w1.w, acc.w);
        acc.x = fmaf(fv.z, w2.x, acc.x); acc.y = fmaf(fv.z, w2.y, acc.y);
        acc.z = fmaf(fv.z, w2.z, acc.z); acc.w = fmaf(fv.z, w2.w, acc.w);
        acc.x = fmaf(fv.w, w3.x, acc.x); acc.y = fmaf(fv.w, w3.y, acc.y);
        acc.z = fmaf(fv.w, w3.z, acc.z); acc.w = fmaf(fv.w, w3.w, acc.w);
      }
      *(ushort4*)(h + (size_t)r * COUT_ + o4) =
          make_ushort4(f2bf(acc.x), f2bf(acc.y), f2bf(acc.z), f2bf(acc.w));
      s4.x += acc.x; s4.y += acc.y; s4.z += acc.z; s4.w += acc.w;
      ss4.x = fmaf(acc.x, acc.x, ss4.x); ss4.y = fmaf(acc.y, acc.y, ss4.y);
      ss4.z = fmaf(acc.z, acc.z, ss4.z); ss4.w = fmaf(acc.w, acc.w, ss4.w);
    }
    atomicAdd(&ls[o4 + 0], s4.x); atomicAdd(&ls[o4 + 1], s4.y);
    atomicAdd(&ls[o4 + 2], s4.z); atomicAdd(&ls[o4 + 3], s4.w);
    atomicAdd(&ls[128 + o4 + 0], ss4.x); atomicAdd(&ls[128 + o4 + 1], ss4.y);
    atomicAdd(&ls[128 + o4 + 2], ss4.z); atomicAdd(&ls[128 + o4 + 3], ss4.w);
    __syncthreads();
    if (t < 128) {
      atomicAdd(&stats[t], ls[t]);
      atomicAdd(&stats[128 + t], ls[128 + t]);
    }
    return;
  }

  // ------------------------- kNN split block -------------------------
  {
    const int kid = id - (B_ + 512);
    const int qt = kid / (B_ * S);
    const int rem = kid % (B_ * S);
    const int b = rem / S;
    const int s = rem % S;
    const int KPS = N_ / S;
    const int KT = KPS / 128;
    float* Qs = (float*)smem;
    float* Ks = (float*)(smem + 16384);
    float* sd2 = (float*)(smem + 49152);
    float* qq = (float*)(smem + 82944);
    float* ff = (float*)(smem + 83200);
    int* qid = (int*)(smem + 83712);
    const float* fb = features + (size_t)b * N_ * CIN_;

    if (t == 0) {
      while (__hip_atomic_load(&prog[b], __ATOMIC_ACQUIRE,
                               __HIP_MEMORY_SCOPE_AGENT) < qt + 1)
        __builtin_amdgcn_s_sleep(16);
    }
    __syncthreads();
    if (t < 64) qid[t] = fps_idx[b * M_ + qt * 64 + t];
    __syncthreads();
#pragma unroll
    for (int st = 0; st < 2; ++st) {
      const int iid = t + 512 * st;
      const int row = iid >> 4, c4 = iid & 15;
      const int pc = (c4 + (row >> 2)) & 15;
      const float4 v = *(const float4*)(fb + (size_t)qid[row] * CIN_ + c4 * 4);
      *(float4*)(&Qs[row * 64 + pc * 4]) = v;
    }
    __syncthreads();
    if (t < 64) {
      float sv = 0.f;
#pragma unroll
      for (int c4 = 0; c4 < 16; ++c4) {
        const int pc = (c4 + (t >> 2)) & 15;
        const float4 v = *(const float4*)(&Qs[t * 64 + pc * 4]);
        sv = fmaf(v.x, v.x, sv); sv = fmaf(v.y, v.y, sv);
        sv = fmaf(v.z, v.z, sv); sv = fmaf(v.w, v.w, sv);
      }
      qq[t] = sv;
    }

    u64 lst[16];
#pragma unroll
    for (int p = 0; p < 16; ++p) lst[p] = ~0ull;
    u64 worst = ~0ull;
    int wpos = 0;

    const int q0 = (t >> 5) * 4;
    const int k0 = (t & 31) * 4;
    const int sq = t >> 3;
    const int ssub = t & 7;

    for (int kt = 0; kt < KT; ++kt) {
      const int kb = s * KPS + kt * 128;
#pragma unroll
      for (int st = 0; st < 4; ++st) {
        const int iid = t + 512 * st;
        const int row = iid >> 4, c4 = iid & 15;
        const int pc = (c4 + (row >> 2)) & 15;
        const float4 v =
            *(const float4*)(fb + (size_t)(kb + row) * CIN_ + c4 * 4);
        *(float4*)(&Ks[row * 64 + pc * 4]) = v;
      }
      __syncthreads();
      if (t < 128) {
        float sv = 0.f;
#pragma unroll
        for (int c4 = 0; c4 < 16; ++c4) {
          const int pc = (c4 + (t >> 2)) & 15;
          const float4 v = *(const float4*)(&Ks[t * 64 + pc * 4]);
          sv = fmaf(v.x, v.x, sv); sv = fmaf(v.y, v.y, sv);
          sv = fmaf(v.z, v.z, sv); sv = fmaf(v.w, v.w, sv);
        }
        ff[t] = sv;
      }
      __syncthreads();
      float acc[4][4];
#pragma unroll
      for (int i = 0; i < 4; ++i)
#pragma unroll
        for (int j = 0; j < 4; ++j) acc[i][j] = 0.f;
#pragma unroll
      for (int c4 = 0; c4 < 16; ++c4) {
        float4 qv[4], kv[4];
#pragma unroll
        for (int i = 0; i < 4; ++i) {
          const int row = q0 + i;
          const int pc = (c4 + (row >> 2)) & 15;
          qv[i] = *(const float4*)(&Qs[row * 64 + pc * 4]);
        }
#pragma unroll
        for (int j = 0; j < 4; ++j) {
          const int row = k0 + j;
          const int pc = (c4 + (row >> 2)) & 15;
          kv[j] = *(const float4*)(&Ks[row * 64 + pc * 4]);
        }
#pragma unroll
        for (int i = 0; i < 4; ++i)
#pragma unroll
          for (int j = 0; j < 4; ++j) {
            acc[i][j] = fmaf(qv[i].x, kv[j].x, acc[i][j]);
            acc[i][j] = fmaf(qv[i].y, kv[j].y, acc[i][j]);
            acc[i][j] = fmaf(qv[i].z, kv[j].z, acc[i][j]);
            acc[i][j] = fmaf(qv[i].w, kv[j].w, acc[i][j]);
          }
      }
#pragma unroll
      for (int i = 0; i < 4; ++i) {
        const float qv = qq[q0 + i];
        float4 o;
        o.x = __fsub_rn(__fadd_rn(qv, ff[k0 + 0]), 2.f * acc[i][0]);
        o.y = __fsub_rn(__fadd_rn(qv, ff[k0 + 1]), 2.f * acc[i][1]);
        o.z = __fsub_rn(__fadd_rn(qv, ff[k0 + 2]), 2.f * acc[i][2]);
        o.w = __fsub_rn(__fadd_rn(qv, ff[k0 + 3]), 2.f * acc[i][3]);
        *(float4*)(&sd2[(q0 + i) * 132 + k0]) = o;
      }
      __syncthreads();
#pragma unroll
      for (int g = 0; g < 4; ++g) {
        const float4 v = *(const float4*)(&sd2[sq * 132 + ssub * 16 + g * 4]);
        const float dv[4] = {v.x, v.y, v.z, v.w};
#pragma unroll
        for (int jj = 0; jj < 4; ++jj) {
          const int key = kb + ssub * 16 + g * 4 + jj;
          const u64 pk = ((u64)mono32(dv[jj]) << 32) | (unsigned)key;
          if (pk < worst) {
#pragma unroll
            for (int p = 0; p < 16; ++p)
              if (p == wpos) lst[p] = pk;
            worst = lst[0]; wpos = 0;
#pragma unroll
            for (int p = 1; p < 16; ++p)
              if (lst[p] > worst) { worst = lst[p]; wpos = p; }
          }
        }
      }
      __syncthreads();
    }
    u64* cb = cand + ((size_t)(b * M_ + qt * 64 + sq) * S + s) * 16;
    for (int r = 0; r < K_; ++r) {
      u64 mn = lst[0];
#pragma unroll
      for (int p = 1; p < 16; ++p)
        if (lst[p] < mn) mn = lst[p];
      u64 m2 = mn;
#pragma unroll
      for (int off = 1; off < 8; off <<= 1) {
        const u64 o = __shfl_xor(m2, off, 64);
        if (o < m2) m2 = o;
      }
      if (mn == m2) {
        bool done = false;
#pragma unroll
        for (int p = 0; p < 16; ++p)
          if (!done && lst[p] == m2) { lst[p] = ~0ull; done = true; }
      }
      if (ssub == 0) cb[r] = m2;
    }
  }
}

// finalize (redundant per block) + merge S sorted lists + gather + tail.
__global__ __launch_bounds__(256) void gather_tail_kernel(
    const float* __restrict__ pos, const int* __restrict__ fps_idx,
    const unsigned short* __restrict__ h, const float* __restrict__ ctrl,
    const float* __restrict__ gamma, const float* __restrict__ beta,
    const u64* __restrict__ cand, float* __restrict__ out, int S,
    int batch_as_i64) {
  const int g = blockIdx.x;
  const int t = threadIdx.x;
  const int A = B_ * M_ * COUT_;
  const int P = B_ * M_ * 3;
  if (g >= B_ * M_ / 2) {  // 16 tail blocks
    const int gid2 = (g - B_ * M_ / 2) * 256 + t;
    for (int i = 0; i < 16; ++i) {
      const int gid = gid2 + 4096 * i;
      if (gid < P) {
        const int Q = gid / 3;
        const int c = gid - Q * 3;
        const int b = Q >> 10;
        const int idx = fps_idx[Q];
        out[A + gid] = pos[((size_t)b * N_ + idx) * 3 + c];
      } else {
        const int Q = gid - P;
        if (Q < B_ * M_) {
          const int b = Q >> 10;
          float* base = out + A + P;
          if (batch_as_i64)
            ((long long*)base)[Q] = (long long)b;
          else
            base[Q] = (float)b;
        }
      }
    }
    return;
  }
  __shared__ u64 cl[2][128];
  __shared__ int nbi[32];
  __shared__ float scsh[256];
  if (t < 128) {
    const float inv = 1.0f / (float)(B_ * N_);
    const float mean = ctrl[t] * inv;
    const float var = ctrl[128 + t] * inv - mean * mean;
    const float r = 1.0f / sqrtf(var + 1e-5f);
    const float sc = gamma[t] * r;
    scsh[t] = sc;
    scsh[128 + t] = beta[t] - mean * sc;
  }
  const int S16 = S * 16;
  const int Q0 = g * 2;
  if (t < 2 * S16) {
    const int qi = t / S16, sl = t % S16;
    cl[qi][sl] = cand[(size_t)(Q0 + qi) * S16 + sl];
  }
  __syncthreads();
  if ((t & 127) == 0) {
    const int qi = t >> 7;
    int ptr[8] = {0, 0, 0, 0, 0, 0, 0, 0};
    for (int r = 0; r < K_; ++r) {
      u64 mn = ~0ull;
      int ms = 0;
      for (int s = 0; s < S; ++s) {
        if (ptr[s] < 16) {
          const u64 v = cl[qi][s * 16 + ptr[s]];
          if (v < mn) { mn = v; ms = s; }
        }
      }
      nbi[qi * 16 + r] = (int)(unsigned)(mn & 0xFFFFFFFFu);
      ptr[ms]++;
    }
  }
  __syncthreads();
  const int q2 = t >> 7, o = t & 127;
  const int Q = Q0 + q2, b = Q >> 10;
  const float sc = scsh[o];
  const float sh = scsh[128 + o];
  float mx = -3.402823466e38f;
#pragma unroll
  for (int k = 0; k < K_; ++k) {
    const int n = nbi[q2 * 16 + k];
    const float v = fmaf(
        __uint_as_float((unsigned)h[((size_t)b * N_ + n) * COUT_ + o] << 16),
        sc, sh);
    mx = fmaxf(mx, v);
  }
  out[(size_t)Q * COUT_ + o] = mx;
}

extern "C" void kernel_launch(void* const* d_in, const int* in_sizes, int n_in,
                              void* d_out, int out_size, void* d_ws, size_t ws_size,
                              hipStream_t stream) {
  const float* features = (const float*)d_in[0];
  const float* positions = (const float*)d_in[1];
  const float* W = (const float*)d_in[3];
  const float* bias = (const float*)d_in[4];
  const float* gamma = (const float*)d_in[5];
  const float* beta = (const float*)d_in[6];
  float* out = (float*)d_out;
  unsigned char* ws = (unsigned char*)d_ws;

  int* fps_idx = (int*)ws;                            // 64 KB
  unsigned short* h = (unsigned short*)(ws + 65536);  // bf16, 16.8 MB
  const size_t hoff = 65536 + (size_t)B_ * N_ * COUT_ * 2;
  float* ctrl = (float*)(ws + hoff);                  // 4 KB
  u64* cand = (u64*)(ws + hoff + 4096);
  const size_t base = hoff + 4096;

  int S = 8;
  while (S > 1 && base + (size_t)B_ * M_ * S * 16 * 8 > ws_size) S >>= 1;

  const int rem = out_size - (B_ * M_ * COUT_) - (B_ * M_ * 3);
  const int batch_as_i64 = (rem >= 2 * B_ * M_) ? 1 : 0;

  hipMemsetAsync(ctrl, 0, 4096, stream);
  mega_kernel<<<B_ + 512 + 256 * S, 512, 0, stream>>>(
      positions, features, W, bias, fps_idx, h, ctrl, cand, S);
  gather_tail_kernel<<<B_ * M_ / 2 + 16, 256, 0, stream>>>(
      positions, fps_idx, h, ctrl, gamma, beta, cand, out, S, batch_as_i64);
}

// Round 8
// 1080.603 us; speedup vs baseline: 1.5637x; 1.5637x over previous
//
#include <hip/hip_runtime.h>

#define B_ 16
#define N_ 4096
#define CIN_ 64
#define COUT_ 128
#define K_ 16
#define M_ 1024

typedef float f32x2 __attribute__((ext_vector_type(2)));
typedef unsigned long long u64;

#define DPPF(m, ctrl)                                                          \
  m = fmaxf(m, __int_as_float(__builtin_amdgcn_update_dpp(                     \
                  0, __float_as_int(m), ctrl, 0xF, 0xF, true)))
#define DPPI(e, ctrl)                                                          \
  e = max(e, __builtin_amdgcn_update_dpp(0, e, ctrl, 0xF, 0xF, true))

__device__ __forceinline__ unsigned mono32(float d) {
  unsigned u = __float_as_uint(d);
  return u ^ (unsigned)(((int)u >> 31) | 0x80000000);
}
__device__ __forceinline__ unsigned short f2bf(float x) {
  const unsigned u = __float_as_uint(x);
  return (unsigned short)((u + 0x7FFF + ((u >> 16) & 1)) >> 16);  // RNE
}

// ctrl (float*) layout, zeroed by memset: [0..512) stats sums (floats);
// byte 2048: prog[16] (int); byte 2112: ticket counter (int).
// Roles: [0,16) FPS | [16,528) linear+stats | [528,768) persistent kNN workers.
__global__ __launch_bounds__(512) void mega_kernel(
    const float* __restrict__ pos, const float* __restrict__ features,
    const float* __restrict__ W, const float* __restrict__ bias,
    int* __restrict__ fps_idx, unsigned short* __restrict__ h,
    float* __restrict__ ctrl, u64* __restrict__ cand, int S) {
  __shared__ __align__(16) char smem[84 * 1024];
  const int id = blockIdx.x;
  const int t = threadIdx.x;
  float* stats = ctrl;
  int* prog = (int*)(ctrl + 512);
  int* tickets = (int*)(ctrl + 528);

  if (id < B_) {
    // ---- FPS (R5-proven): 256 lanes, tagged 4-slot spin-poll reduce ----
    const int b = id;
    float4* P = (float4*)smem;                          // 64 KB
    volatile u64* red = (volatile u64*)(smem + 65536);  // [2][4], tagged
    const float* pb = pos + (size_t)b * N_ * 3;
    if (t < 8) ((u64*)(smem + 65536))[t] = 0;  // tag 0 != any step >= 1
    for (int i = t; i < N_; i += 512)
      P[i] = make_float4(pb[i * 3], pb[i * 3 + 1], pb[i * 3 + 2], 0.f);
    __syncthreads();
    if (t >= 256) return;
    f32x2 px[8], py[8], pz[8], md[8];
#pragma unroll
    for (int j = 0; j < 8; ++j) {
      const float4 lo = P[t + 512 * j];
      const float4 hi = P[t + 512 * j + 256];
      px[j] = (f32x2){lo.x, hi.x};
      py[j] = (f32x2){lo.y, hi.y};
      pz[j] = (f32x2){lo.z, hi.z};
      md[j] = (f32x2){1e10f, 1e10f};
    }
    if (t == 0) fps_idx[b * M_] = 0;
    const int wv = t >> 6, ln = t & 63;
    const int e0 = 65535 - t;  // enc = 65535 - idx; idx = t + 256*(2j+h)
    float4 lp = P[0];
    for (int step = 1; step < M_; ++step) {
      const f32x2 lx = {lp.x, lp.x}, ly = {lp.y, lp.y}, lz = {lp.z, lp.z};
      float bestd = -1.0f;
      int be = 0;
      {
#pragma clang fp contract(off)
#pragma unroll
        for (int j = 0; j < 8; ++j) {
          const f32x2 dx = px[j] - lx;
          const f32x2 dy = py[j] - ly;
          const f32x2 dz = pz[j] - lz;
          const f32x2 s1 = dx * dx;
          const f32x2 s2 = dy * dy;
          const f32x2 s3 = dz * dz;
          const f32x2 d = (s1 + s2) + s3;  // exact reference order
          f32x2 nd;
          nd.x = fminf(md[j].x, d.x);
          nd.y = fminf(md[j].y, d.y);
          md[j] = nd;
          if (nd.x > bestd) { bestd = nd.x; be = e0 - (j << 9); }
          if (nd.y > bestd) { bestd = nd.y; be = e0 - (j << 9) - 256; }
        }
      }
      float m = bestd;
      DPPF(m, 0x111); DPPF(m, 0x112); DPPF(m, 0x114); DPPF(m, 0x118);
      DPPF(m, 0x142); DPPF(m, 0x143);
      const float wm =
          __int_as_float(__builtin_amdgcn_readlane(__float_as_int(m), 63));
      int enc = (bestd == wm) ? be : 0;
      DPPI(enc, 0x111); DPPI(enc, 0x112); DPPI(enc, 0x114); DPPI(enc, 0x118);
      DPPI(enc, 0x142); DPPI(enc, 0x143);
      const int wenc = __builtin_amdgcn_readlane(enc, 63);
      const unsigned tag = (unsigned)(step & 1023);
      volatile u64* rb = red + (step & 1) * 4;
      if (ln == 0)
        rb[wv] = ((u64)__float_as_uint(wm) << 32) | ((u64)tag << 16) |
                 (unsigned)wenc;
      u64 r0, r1, r2, r3;
      for (;;) {
        r0 = rb[0]; r1 = rb[1]; r2 = rb[2]; r3 = rb[3];
        const u64 x = ((r0 >> 16) ^ tag) | ((r1 >> 16) ^ tag) |
                      ((r2 >> 16) ^ tag) | ((r3 >> 16) ^ tag);
        if (!(x & 0x3FF)) break;
      }
      u64 rr = r0 > r1 ? r0 : r1;
      const u64 r2m = r2 > r3 ? r2 : r3;
      if (r2m > rr) rr = r2m;
      const int last = 65535 - (int)(unsigned)(rr & 0xFFFFu);
      lp = P[last];
      if (t == 0) {
        fps_idx[b * M_ + step] = last;
        if ((step & 63) == 63)
          __hip_atomic_store(&prog[b], (step >> 6) + 1, __ATOMIC_RELEASE,
                             __HIP_MEMORY_SCOPE_AGENT);
      }
    }
    return;
  }

  if (id < B_ + 512) {
    // ---------------- linear (h bf16) + stats partials ----------------
    const int lid = id - B_;
    float* ls = (float*)smem;  // 256 floats
    for (int i = t; i < 256; i += 512) ls[i] = 0.f;
    __syncthreads();
    const int o4 = (t & 31) << 2;
    const int rl = t >> 5;
    const float4 bv = *(const float4*)(bias + o4);
    float4 s4 = {0, 0, 0, 0}, ss4 = {0, 0, 0, 0};
    for (int i = 0; i < 8; ++i) {
      const int r = lid * 128 + rl * 8 + i;
      const float4* fr = (const float4*)(features + (size_t)r * CIN_);
      float4 acc = bv;
#pragma unroll
      for (int c4 = 0; c4 < 16; ++c4) {
        const float4 fv = fr[c4];
        const float* wr = W + (size_t)(c4 * 4) * COUT_ + o4;
        const float4 w0 = *(const float4*)(wr);
        const float4 w1 = *(const float4*)(wr + COUT_);
        const float4 w2 = *(const float4*)(wr + 2 * COUT_);
        const float4 w3 = *(const float4*)(wr + 3 * COUT_);
        acc.x = fmaf(fv.x, w0.x, acc.x); acc.y = fmaf(fv.x, w0.y, acc.y);
        acc.z = fmaf(fv.x, w0.z, acc.z); acc.w = fmaf(fv.x, w0.w, acc.w);
        acc.x = fmaf(fv.y, w1.x, acc.x); acc.y = fmaf(fv.y, w1.y, acc.y);
        acc.z = fmaf(fv.y, w1.z, acc.z); acc.w = fmaf(fv.y, w1.w, acc.w);
        acc.x = fmaf(fv.z, w2.x, acc.x); acc.y = fmaf(fv.z, w2.y, acc.y);
        acc.z = fmaf(fv.z, w2.z, acc.z); acc.w = fmaf(fv.z, w2.w, acc.w);
        acc.x = fmaf(fv.w, w3.x, acc.x); acc.y = fmaf(fv.w, w3.y, acc.y);
        acc.z = fmaf(fv.w, w3.z, acc.z); acc.w = fmaf(fv.w, w3.w, acc.w);
      }
      *(ushort4*)(h + (size_t)r * COUT_ + o4) =
          make_ushort4(f2bf(acc.x), f2bf(acc.y), f2bf(acc.z), f2bf(acc.w));
      s4.x += acc.x; s4.y += acc.y; s4.z += acc.z; s4.w += acc.w;
      ss4.x = fmaf(acc.x, acc.x, ss4.x); ss4.y = fmaf(acc.y, acc.y, ss4.y);
      ss4.z = fmaf(acc.z, acc.z, ss4.z); ss4.w = fmaf(acc.w, acc.w, ss4.w);
    }
    atomicAdd(&ls[o4 + 0], s4.x); atomicAdd(&ls[o4 + 1], s4.y);
    atomicAdd(&ls[o4 + 2], s4.z); atomicAdd(&ls[o4 + 3], s4.w);
    atomicAdd(&ls[128 + o4 + 0], ss4.x); atomicAdd(&ls[128 + o4 + 1], ss4.y);
    atomicAdd(&ls[128 + o4 + 2], ss4.z); atomicAdd(&ls[128 + o4 + 3], ss4.w);
    __syncthreads();
    if (t < 128) {
      atomicAdd(&stats[t], ls[t]);
      atomicAdd(&stats[128 + t], ls[128 + t]);
    }
    return;
  }

  // ---------------- persistent kNN workers: ticket queue ----------------
  {
    float* Qs = (float*)smem;
    float* Ks = (float*)(smem + 16384);
    float* sd2 = (float*)(smem + 49152);
    float* qq = (float*)(smem + 82944);
    float* ff = (float*)(smem + 83200);
    int* qid = (int*)(smem + 83712);
    int* tk = (int*)(smem + 83968);
    const int NT = 256 * S;  // total tickets, qt-major
    const int q0 = (t >> 5) * 4;
    const int k0 = (t & 31) * 4;
    const int sq = t >> 3;
    const int ssub = t & 7;
    const int KPS = N_ / S;
    const int KT = KPS / 128;

    for (;;) {
      if (t == 0)
        *tk = __hip_atomic_fetch_add(tickets, 1, __ATOMIC_RELAXED,
                                     __HIP_MEMORY_SCOPE_AGENT);
      __syncthreads();
      const int ticket = *tk;
      if (ticket >= NT) return;
      const int qt = ticket / (B_ * S);
      const int rem = ticket % (B_ * S);
      const int b = rem / S;
      const int s = rem % S;
      const float* fb = features + (size_t)b * N_ * CIN_;

      if (t == 0) {
        while (__hip_atomic_load(&prog[b], __ATOMIC_ACQUIRE,
                                 __HIP_MEMORY_SCOPE_AGENT) < qt + 1)
          __builtin_amdgcn_s_sleep(16);
      }
      __syncthreads();
      if (t < 64) qid[t] = fps_idx[b * M_ + qt * 64 + t];
      __syncthreads();
#pragma unroll
      for (int st = 0; st < 2; ++st) {
        const int iid = t + 512 * st;
        const int row = iid >> 4, c4 = iid & 15;
        const int pc = (c4 + (row >> 2)) & 15;
        const float4 v = *(const float4*)(fb + (size_t)qid[row] * CIN_ + c4 * 4);
        *(float4*)(&Qs[row * 64 + pc * 4]) = v;
      }
      __syncthreads();
      if (t < 64) {
        float sv = 0.f;
#pragma unroll
        for (int c4 = 0; c4 < 16; ++c4) {
          const int pc = (c4 + (t >> 2)) & 15;
          const float4 v = *(const float4*)(&Qs[t * 64 + pc * 4]);
          sv = fmaf(v.x, v.x, sv); sv = fmaf(v.y, v.y, sv);
          sv = fmaf(v.z, v.z, sv); sv = fmaf(v.w, v.w, sv);
        }
        qq[t] = sv;
      }

      u64 lst[16];
#pragma unroll
      for (int p = 0; p < 16; ++p) lst[p] = ~0ull;
      u64 worst = ~0ull;
      int wpos = 0;

      for (int kt = 0; kt < KT; ++kt) {
        const int kb = s * KPS + kt * 128;
#pragma unroll
        for (int st = 0; st < 4; ++st) {
          const int iid = t + 512 * st;
          const int row = iid >> 4, c4 = iid & 15;
          const int pc = (c4 + (row >> 2)) & 15;
          const float4 v =
              *(const float4*)(fb + (size_t)(kb + row) * CIN_ + c4 * 4);
          *(float4*)(&Ks[row * 64 + pc * 4]) = v;
        }
        __syncthreads();
        if (t < 128) {
          float sv = 0.f;
#pragma unroll
          for (int c4 = 0; c4 < 16; ++c4) {
            const int pc = (c4 + (t >> 2)) & 15;
            const float4 v = *(const float4*)(&Ks[t * 64 + pc * 4]);
            sv = fmaf(v.x, v.x, sv); sv = fmaf(v.y, v.y, sv);
            sv = fmaf(v.z, v.z, sv); sv = fmaf(v.w, v.w, sv);
          }
          ff[t] = sv;
        }
        __syncthreads();
        float acc[4][4];
#pragma unroll
        for (int i = 0; i < 4; ++i)
#pragma unroll
          for (int j = 0; j < 4; ++j) acc[i][j] = 0.f;
#pragma unroll
        for (int c4 = 0; c4 < 16; ++c4) {
          float4 qv[4], kv[4];
#pragma unroll
          for (int i = 0; i < 4; ++i) {
            const int row = q0 + i;
            const int pc = (c4 + (row >> 2)) & 15;
            qv[i] = *(const float4*)(&Qs[row * 64 + pc * 4]);
          }
#pragma unroll
          for (int j = 0; j < 4; ++j) {
            const int row = k0 + j;
            const int pc = (c4 + (row >> 2)) & 15;
            kv[j] = *(const float4*)(&Ks[row * 64 + pc * 4]);
          }
#pragma unroll
          for (int i = 0; i < 4; ++i)
#pragma unroll
            for (int j = 0; j < 4; ++j) {
              acc[i][j] = fmaf(qv[i].x, kv[j].x, acc[i][j]);
              acc[i][j] = fmaf(qv[i].y, kv[j].y, acc[i][j]);
              acc[i][j] = fmaf(qv[i].z, kv[j].z, acc[i][j]);
              acc[i][j] = fmaf(qv[i].w, kv[j].w, acc[i][j]);
            }
        }
#pragma unroll
        for (int i = 0; i < 4; ++i) {
          const float qv = qq[q0 + i];
          float4 o;
          o.x = __fsub_rn(__fadd_rn(qv, ff[k0 + 0]), 2.f * acc[i][0]);
          o.y = __fsub_rn(__fadd_rn(qv, ff[k0 + 1]), 2.f * acc[i][1]);
          o.z = __fsub_rn(__fadd_rn(qv, ff[k0 + 2]), 2.f * acc[i][2]);
          o.w = __fsub_rn(__fadd_rn(qv, ff[k0 + 3]), 2.f * acc[i][3]);
          *(float4*)(&sd2[(q0 + i) * 132 + k0]) = o;
        }
        __syncthreads();
#pragma unroll
        for (int g = 0; g < 4; ++g) {
          const float4 v = *(const float4*)(&sd2[sq * 132 + ssub * 16 + g * 4]);
          const float dv[4] = {v.x, v.y, v.z, v.w};
#pragma unroll
          for (int jj = 0; jj < 4; ++jj) {
            const int key = kb + ssub * 16 + g * 4 + jj;
            const u64 pk = ((u64)mono32(dv[jj]) << 32) | (unsigned)key;
            if (pk < worst) {
#pragma unroll
              for (int p = 0; p < 16; ++p)
                if (p == wpos) lst[p] = pk;
              worst = lst[0]; wpos = 0;
#pragma unroll
              for (int p = 1; p < 16; ++p)
                if (lst[p] > worst) { worst = lst[p]; wpos = p; }
            }
          }
        }
        __syncthreads();
      }
      u64* cb = cand + ((size_t)(b * M_ + qt * 64 + sq) * S + s) * 16;
      for (int r = 0; r < K_; ++r) {
        u64 mn = lst[0];
#pragma unroll
        for (int p = 1; p < 16; ++p)
          if (lst[p] < mn) mn = lst[p];
        u64 m2 = mn;
#pragma unroll
        for (int off = 1; off < 8; off <<= 1) {
          const u64 o = __shfl_xor(m2, off, 64);
          if (o < m2) m2 = o;
        }
        if (mn == m2) {
          bool done = false;
#pragma unroll
          for (int p = 0; p < 16; ++p)
            if (!done && lst[p] == m2) { lst[p] = ~0ull; done = true; }
        }
        if (ssub == 0) cb[r] = m2;
      }
    }
  }
}

// Tile-based: 256 merge/gather blocks (one per (b,qt), 64 queries) + 16 tail.
__global__ __launch_bounds__(256) void gather_tail_kernel(
    const float* __restrict__ pos, const int* __restrict__ fps_idx,
    const unsigned short* __restrict__ h, const float* __restrict__ ctrl,
    const float* __restrict__ gamma, const float* __restrict__ beta,
    const u64* __restrict__ cand, float* __restrict__ out, int S,
    int batch_as_i64) {
  const int g = blockIdx.x;
  const int t = threadIdx.x;
  const int A = B_ * M_ * COUT_;
  const int P = B_ * M_ * 3;
  if (g >= 256) {  // tail blocks
    const int gid2 = (g - 256) * 256 + t;
    for (int i = 0; i < 16; ++i) {
      const int gid = gid2 + 4096 * i;
      if (gid < P) {
        const int Q = gid / 3;
        const int c = gid - Q * 3;
        const int b = Q >> 10;
        const int idx = fps_idx[Q];
        out[A + gid] = pos[((size_t)b * N_ + idx) * 3 + c];
      } else {
        const int Q = gid - P;
        if (Q < B_ * M_) {
          const int b = Q >> 10;
          float* base = out + A + P;
          if (batch_as_i64)
            ((long long*)base)[Q] = (long long)b;
          else
            base[Q] = (float)b;
        }
      }
    }
    return;
  }
  __shared__ u64 cl[64 * 128];  // 64 queries x (S*16 <= 128)
  __shared__ int nbi[64 * 16];
  __shared__ float scsh[256];
  const int b = g >> 4, qt = g & 15;
  if (t < 128) {
    const float inv = 1.0f / (float)(B_ * N_);
    const float mean = ctrl[t] * inv;
    const float var = ctrl[128 + t] * inv - mean * mean;
    const float r = 1.0f / sqrtf(var + 1e-5f);
    const float sc = gamma[t] * r;
    scsh[t] = sc;
    scsh[128 + t] = beta[t] - mean * sc;
  }
  const int S16 = S * 16;
  const u64* cg = cand + (size_t)(b * M_ + qt * 64) * S16;
  for (int i = t; i < 64 * S16; i += 256) cl[i] = cg[i];
  __syncthreads();
  if (t < 64) {  // exact S-way sorted merge, query t
    int ptr[8] = {0, 0, 0, 0, 0, 0, 0, 0};
    for (int r = 0; r < K_; ++r) {
      u64 mn = ~0ull;
      int ms = 0;
      for (int s = 0; s < S; ++s) {
        if (ptr[s] < 16) {
          const u64 v = cl[t * S16 + s * 16 + ptr[s]];
          if (v < mn) { mn = v; ms = s; }
        }
      }
      nbi[t * 16 + r] = (int)(unsigned)(mn & 0xFFFFFFFFu);
      ptr[ms]++;
    }
  }
  __syncthreads();
  // gather: 4 lanes/query x 32 channels; min+max so BN sign is safe post-pool
  const int q = t >> 2;
  const int c0 = (t & 3) * 32;
  float mx[32], mn[32];
#pragma unroll
  for (int i = 0; i < 32; ++i) { mx[i] = -3.402823466e38f; mn[i] = 3.402823466e38f; }
#pragma unroll
  for (int k = 0; k < K_; ++k) {
    const int n = nbi[q * 16 + k];
    const uint4* hr = (const uint4*)(h + ((size_t)b * N_ + n) * COUT_ + c0);
#pragma unroll
    for (int j = 0; j < 4; ++j) {
      const uint4 hv = hr[j];
      const unsigned hu[4] = {hv.x, hv.y, hv.z, hv.w};
#pragma unroll
      for (int i = 0; i < 4; ++i) {
        const float lo = __uint_as_float(hu[i] << 16);
        const float hi = __uint_as_float(hu[i] & 0xFFFF0000u);
        const int c = j * 8 + 2 * i;
        mx[c] = fmaxf(mx[c], lo); mn[c] = fminf(mn[c], lo);
        mx[c + 1] = fmaxf(mx[c + 1], hi); mn[c + 1] = fminf(mn[c + 1], hi);
      }
    }
  }
  float* ob = out + (size_t)(b * M_ + qt * 64 + q) * COUT_ + c0;
#pragma unroll
  for (int i = 0; i < 8; ++i) {
    float4 o;
#pragma unroll
    for (int e = 0; e < 4; ++e) {
      const int c = 4 * i + e;
      const float sc = scsh[c0 + c], sh = scsh[128 + c0 + c];
      const float v = sc >= 0.f ? mx[c] : mn[c];
      (&o.x)[e] = fmaf(v, sc, sh);
    }
    *(float4*)(ob + 4 * i) = o;
  }
}

extern "C" void kernel_launch(void* const* d_in, const int* in_sizes, int n_in,
                              void* d_out, int out_size, void* d_ws, size_t ws_size,
                              hipStream_t stream) {
  const float* features = (const float*)d_in[0];
  const float* positions = (const float*)d_in[1];
  const float* W = (const float*)d_in[3];
  const float* bias = (const float*)d_in[4];
  const float* gamma = (const float*)d_in[5];
  const float* beta = (const float*)d_in[6];
  float* out = (float*)d_out;
  unsigned char* ws = (unsigned char*)d_ws;

  int* fps_idx = (int*)ws;                            // 64 KB
  unsigned short* h = (unsigned short*)(ws + 65536);  // bf16, 16.8 MB
  const size_t hoff = 65536 + (size_t)B_ * N_ * COUT_ * 2;
  float* ctrl = (float*)(ws + hoff);                  // 4 KB
  u64* cand = (u64*)(ws + hoff + 4096);
  const size_t base = hoff + 4096;

  int S = 8;
  while (S > 1 && base + (size_t)B_ * M_ * S * 16 * 8 > ws_size) S >>= 1;

  const int rem = out_size - (B_ * M_ * COUT_) - (B_ * M_ * 3);
  const int batch_as_i64 = (rem >= 2 * B_ * M_) ? 1 : 0;

  hipMemsetAsync(ctrl, 0, 4096, stream);
  mega_kernel<<<B_ + 512 + 240, 512, 0, stream>>>(
      positions, features, W, bias, fps_idx, h, ctrl, cand, S);
  gather_tail_kernel<<<256 + 16, 256, 0, stream>>>(
      positions, fps_idx, h, ctrl, gamma, beta, cand, out, S, batch_as_i64);
}

// Round 9
// 891.065 us; speedup vs baseline: 1.8963x; 1.2127x over previous
//
#include <hip/hip_runtime.h>

#define B_ 16
#define N_ 4096
#define CIN_ 64
#define COUT_ 128
#define K_ 16
#define M_ 1024

typedef float f32x2 __attribute__((ext_vector_type(2)));
typedef unsigned long long u64;

#define DPPF(m, ctrl)                                                          \
  m = fmaxf(m, __int_as_float(__builtin_amdgcn_update_dpp(                     \
                  0, __float_as_int(m), ctrl, 0xF, 0xF, true)))
#define DPPI(e, ctrl)                                                          \
  e = max(e, __builtin_amdgcn_update_dpp(0, e, ctrl, 0xF, 0xF, true))

__device__ __forceinline__ unsigned mono32(float d) {
  unsigned u = __float_as_uint(d);
  return u ^ (unsigned)(((int)u >> 31) | 0x80000000);
}
__device__ __forceinline__ unsigned short f2bf(float x) {
  const unsigned u = __float_as_uint(x);
  return (unsigned short)((u + 0x7FFF + ((u >> 16) & 1)) >> 16);  // RNE
}

// ctrl (float*), zeroed by memset: [0..512) stats sums; byte 2048: prog[16].
// Roles: [0,16) FPS | [16,528) linear+stats | [528, 528+256*S) one-shot kNN
// split blocks, qt-major (R5-proven: in-order dispatch co-schedules the S
// splits of a tile -> L2 locality + tight release-to-run matching).
__global__ __launch_bounds__(512) void mega_kernel(
    const float* __restrict__ pos, const float* __restrict__ features,
    const float* __restrict__ W, const float* __restrict__ bias,
    int* __restrict__ fps_idx, unsigned short* __restrict__ h,
    float* __restrict__ ctrl, u64* __restrict__ cand, int S) {
  __shared__ __align__(16) char smem[84 * 1024];
  const int id = blockIdx.x;
  const int t = threadIdx.x;
  float* stats = ctrl;
  int* prog = (int*)(ctrl + 512);

  if (id < B_) {
    // ---- FPS (R5-proven): 256 lanes, tagged 4-slot spin-poll reduce ----
    const int b = id;
    float4* P = (float4*)smem;                          // 64 KB
    volatile u64* red = (volatile u64*)(smem + 65536);  // [2][4], tagged
    const float* pb = pos + (size_t)b * N_ * 3;
    if (t < 8) ((u64*)(smem + 65536))[t] = 0;  // tag 0 != any step >= 1
    for (int i = t; i < N_; i += 512)
      P[i] = make_float4(pb[i * 3], pb[i * 3 + 1], pb[i * 3 + 2], 0.f);
    __syncthreads();
    if (t >= 256) return;
    f32x2 px[8], py[8], pz[8], md[8];
#pragma unroll
    for (int j = 0; j < 8; ++j) {
      const float4 lo = P[t + 512 * j];
      const float4 hi = P[t + 512 * j + 256];
      px[j] = (f32x2){lo.x, hi.x};
      py[j] = (f32x2){lo.y, hi.y};
      pz[j] = (f32x2){lo.z, hi.z};
      md[j] = (f32x2){1e10f, 1e10f};
    }
    if (t == 0) fps_idx[b * M_] = 0;
    const int wv = t >> 6, ln = t & 63;
    const int e0 = 65535 - t;  // enc = 65535 - idx; idx = t + 256*(2j+h)
    float4 lp = P[0];
    for (int step = 1; step < M_; ++step) {
      const f32x2 lx = {lp.x, lp.x}, ly = {lp.y, lp.y}, lz = {lp.z, lp.z};
      float bestd = -1.0f;
      int be = 0;
      {
#pragma clang fp contract(off)
#pragma unroll
        for (int j = 0; j < 8; ++j) {
          const f32x2 dx = px[j] - lx;
          const f32x2 dy = py[j] - ly;
          const f32x2 dz = pz[j] - lz;
          const f32x2 s1 = dx * dx;
          const f32x2 s2 = dy * dy;
          const f32x2 s3 = dz * dz;
          const f32x2 d = (s1 + s2) + s3;  // exact reference order
          f32x2 nd;
          nd.x = fminf(md[j].x, d.x);
          nd.y = fminf(md[j].y, d.y);
          md[j] = nd;
          if (nd.x > bestd) { bestd = nd.x; be = e0 - (j << 9); }
          if (nd.y > bestd) { bestd = nd.y; be = e0 - (j << 9) - 256; }
        }
      }
      float m = bestd;
      DPPF(m, 0x111); DPPF(m, 0x112); DPPF(m, 0x114); DPPF(m, 0x118);
      DPPF(m, 0x142); DPPF(m, 0x143);
      const float wm =
          __int_as_float(__builtin_amdgcn_readlane(__float_as_int(m), 63));
      int enc = (bestd == wm) ? be : 0;
      DPPI(enc, 0x111); DPPI(enc, 0x112); DPPI(enc, 0x114); DPPI(enc, 0x118);
      DPPI(enc, 0x142); DPPI(enc, 0x143);
      const int wenc = __builtin_amdgcn_readlane(enc, 63);
      const unsigned tag = (unsigned)(step & 1023);
      volatile u64* rb = red + (step & 1) * 4;
      if (ln == 0)
        rb[wv] = ((u64)__float_as_uint(wm) << 32) | ((u64)tag << 16) |
                 (unsigned)wenc;
      u64 r0, r1, r2, r3;
      for (;;) {
        r0 = rb[0]; r1 = rb[1]; r2 = rb[2]; r3 = rb[3];
        const u64 x = ((r0 >> 16) ^ tag) | ((r1 >> 16) ^ tag) |
                      ((r2 >> 16) ^ tag) | ((r3 >> 16) ^ tag);
        if (!(x & 0x3FF)) break;
      }
      u64 rr = r0 > r1 ? r0 : r1;
      const u64 r2m = r2 > r3 ? r2 : r3;
      if (r2m > rr) rr = r2m;
      const int last = 65535 - (int)(unsigned)(rr & 0xFFFFu);
      lp = P[last];
      if (t == 0) {
        fps_idx[b * M_ + step] = last;
        if ((step & 63) == 63)
          __hip_atomic_store(&prog[b], (step >> 6) + 1, __ATOMIC_RELEASE,
                             __HIP_MEMORY_SCOPE_AGENT);
      }
    }
    return;
  }

  if (id < B_ + 512) {
    // ---------------- linear (h bf16) + stats partials ----------------
    const int lid = id - B_;
    float* ls = (float*)smem;  // 256 floats
    for (int i = t; i < 256; i += 512) ls[i] = 0.f;
    __syncthreads();
    const int o4 = (t & 31) << 2;
    const int rl = t >> 5;
    const float4 bv = *(const float4*)(bias + o4);
    float4 s4 = {0, 0, 0, 0}, ss4 = {0, 0, 0, 0};
    for (int i = 0; i < 8; ++i) {
      const int r = lid * 128 + rl * 8 + i;
      const float4* fr = (const float4*)(features + (size_t)r * CIN_);
      float4 acc = bv;
#pragma unroll
      for (int c4 = 0; c4 < 16; ++c4) {
        const float4 fv = fr[c4];
        const float* wr = W + (size_t)(c4 * 4) * COUT_ + o4;
        const float4 w0 = *(const float4*)(wr);
        const float4 w1 = *(const float4*)(wr + COUT_);
        const float4 w2 = *(const float4*)(wr + 2 * COUT_);
        const float4 w3 = *(const float4*)(wr + 3 * COUT_);
        acc.x = fmaf(fv.x, w0.x, acc.x); acc.y = fmaf(fv.x, w0.y, acc.y);
        acc.z = fmaf(fv.x, w0.z, acc.z); acc.w = fmaf(fv.x, w0.w, acc.w);
        acc.x = fmaf(fv.y, w1.x, acc.x); acc.y = fmaf(fv.y, w1.y, acc.y);
        acc.z = fmaf(fv.y, w1.z, acc.z); acc.w = fmaf(fv.y, w1.w, acc.w);
        acc.x = fmaf(fv.z, w2.x, acc.x); acc.y = fmaf(fv.z, w2.y, acc.y);
        acc.z = fmaf(fv.z, w2.z, acc.z); acc.w = fmaf(fv.z, w2.w, acc.w);
        acc.x = fmaf(fv.w, w3.x, acc.x); acc.y = fmaf(fv.w, w3.y, acc.y);
        acc.z = fmaf(fv.w, w3.z, acc.z); acc.w = fmaf(fv.w, w3.w, acc.w);
      }
      *(ushort4*)(h + (size_t)r * COUT_ + o4) =
          make_ushort4(f2bf(acc.x), f2bf(acc.y), f2bf(acc.z), f2bf(acc.w));
      s4.x += acc.x; s4.y += acc.y; s4.z += acc.z; s4.w += acc.w;
      ss4.x = fmaf(acc.x, acc.x, ss4.x); ss4.y = fmaf(acc.y, acc.y, ss4.y);
      ss4.z = fmaf(acc.z, acc.z, ss4.z); ss4.w = fmaf(acc.w, acc.w, ss4.w);
    }
    atomicAdd(&ls[o4 + 0], s4.x); atomicAdd(&ls[o4 + 1], s4.y);
    atomicAdd(&ls[o4 + 2], s4.z); atomicAdd(&ls[o4 + 3], s4.w);
    atomicAdd(&ls[128 + o4 + 0], ss4.x); atomicAdd(&ls[128 + o4 + 1], ss4.y);
    atomicAdd(&ls[128 + o4 + 2], ss4.z); atomicAdd(&ls[128 + o4 + 3], ss4.w);
    __syncthreads();
    if (t < 128) {
      atomicAdd(&stats[t], ls[t]);
      atomicAdd(&stats[128 + t], ls[128 + t]);
    }
    return;
  }

  // ------------------- one-shot kNN split block (R5-proven) -----------------
  {
    const int kid = id - (B_ + 512);
    const int qt = kid / (B_ * S);
    const int rem = kid % (B_ * S);
    const int b = rem / S;
    const int s = rem % S;
    const int KPS = N_ / S;
    const int KT = KPS / 128;
    float* Qs = (float*)smem;
    float* Ks = (float*)(smem + 16384);
    float* sd2 = (float*)(smem + 49152);
    float* qq = (float*)(smem + 82944);
    float* ff = (float*)(smem + 83200);
    int* qid = (int*)(smem + 83712);
    const float* fb = features + (size_t)b * N_ * CIN_;

    if (t == 0) {
      while (__hip_atomic_load(&prog[b], __ATOMIC_ACQUIRE,
                               __HIP_MEMORY_SCOPE_AGENT) < qt + 1)
        __builtin_amdgcn_s_sleep(16);
    }
    __syncthreads();
    if (t < 64) qid[t] = fps_idx[b * M_ + qt * 64 + t];
    __syncthreads();
#pragma unroll
    for (int st = 0; st < 2; ++st) {
      const int iid = t + 512 * st;
      const int row = iid >> 4, c4 = iid & 15;
      const int pc = (c4 + (row >> 2)) & 15;
      const float4 v = *(const float4*)(fb + (size_t)qid[row] * CIN_ + c4 * 4);
      *(float4*)(&Qs[row * 64 + pc * 4]) = v;
    }
    __syncthreads();
    if (t < 64) {
      float sv = 0.f;
#pragma unroll
      for (int c4 = 0; c4 < 16; ++c4) {
        const int pc = (c4 + (t >> 2)) & 15;
        const float4 v = *(const float4*)(&Qs[t * 64 + pc * 4]);
        sv = fmaf(v.x, v.x, sv); sv = fmaf(v.y, v.y, sv);
        sv = fmaf(v.z, v.z, sv); sv = fmaf(v.w, v.w, sv);
      }
      qq[t] = sv;
    }

    u64 lst[16];
#pragma unroll
    for (int p = 0; p < 16; ++p) lst[p] = ~0ull;
    u64 worst = ~0ull;
    int wpos = 0;

    const int q0 = (t >> 5) * 4;
    const int k0 = (t & 31) * 4;
    const int sq = t >> 3;
    const int ssub = t & 7;

    for (int kt = 0; kt < KT; ++kt) {
      const int kb = s * KPS + kt * 128;
#pragma unroll
      for (int st = 0; st < 4; ++st) {
        const int iid = t + 512 * st;
        const int row = iid >> 4, c4 = iid & 15;
        const int pc = (c4 + (row >> 2)) & 15;
        const float4 v =
            *(const float4*)(fb + (size_t)(kb + row) * CIN_ + c4 * 4);
        *(float4*)(&Ks[row * 64 + pc * 4]) = v;
      }
      __syncthreads();
      if (t < 128) {
        float sv = 0.f;
#pragma unroll
        for (int c4 = 0; c4 < 16; ++c4) {
          const int pc = (c4 + (t >> 2)) & 15;
          const float4 v = *(const float4*)(&Ks[t * 64 + pc * 4]);
          sv = fmaf(v.x, v.x, sv); sv = fmaf(v.y, v.y, sv);
          sv = fmaf(v.z, v.z, sv); sv = fmaf(v.w, v.w, sv);
        }
        ff[t] = sv;
      }
      __syncthreads();
      float acc[4][4];
#pragma unroll
      for (int i = 0; i < 4; ++i)
#pragma unroll
        for (int j = 0; j < 4; ++j) acc[i][j] = 0.f;
#pragma unroll
      for (int c4 = 0; c4 < 16; ++c4) {
        float4 qv[4], kv[4];
#pragma unroll
        for (int i = 0; i < 4; ++i) {
          const int row = q0 + i;
          const int pc = (c4 + (row >> 2)) & 15;
          qv[i] = *(const float4*)(&Qs[row * 64 + pc * 4]);
        }
#pragma unroll
        for (int j = 0; j < 4; ++j) {
          const int row = k0 + j;
          const int pc = (c4 + (row >> 2)) & 15;
          kv[j] = *(const float4*)(&Ks[row * 64 + pc * 4]);
        }
#pragma unroll
        for (int i = 0; i < 4; ++i)
#pragma unroll
          for (int j = 0; j < 4; ++j) {
            acc[i][j] = fmaf(qv[i].x, kv[j].x, acc[i][j]);
            acc[i][j] = fmaf(qv[i].y, kv[j].y, acc[i][j]);
            acc[i][j] = fmaf(qv[i].z, kv[j].z, acc[i][j]);
            acc[i][j] = fmaf(qv[i].w, kv[j].w, acc[i][j]);
          }
      }
#pragma unroll
      for (int i = 0; i < 4; ++i) {
        const float qv = qq[q0 + i];
        float4 o;
        o.x = __fsub_rn(__fadd_rn(qv, ff[k0 + 0]), 2.f * acc[i][0]);
        o.y = __fsub_rn(__fadd_rn(qv, ff[k0 + 1]), 2.f * acc[i][1]);
        o.z = __fsub_rn(__fadd_rn(qv, ff[k0 + 2]), 2.f * acc[i][2]);
        o.w = __fsub_rn(__fadd_rn(qv, ff[k0 + 3]), 2.f * acc[i][3]);
        *(float4*)(&sd2[(q0 + i) * 132 + k0]) = o;
      }
      __syncthreads();
#pragma unroll
      for (int g = 0; g < 4; ++g) {
        const float4 v = *(const float4*)(&sd2[sq * 132 + ssub * 16 + g * 4]);
        const float dv[4] = {v.x, v.y, v.z, v.w};
#pragma unroll
        for (int jj = 0; jj < 4; ++jj) {
          const int key = kb + ssub * 16 + g * 4 + jj;
          const u64 pk = ((u64)mono32(dv[jj]) << 32) | (unsigned)key;
          if (pk < worst) {
#pragma unroll
            for (int p = 0; p < 16; ++p)
              if (p == wpos) lst[p] = pk;
            worst = lst[0]; wpos = 0;
#pragma unroll
            for (int p = 1; p < 16; ++p)
              if (lst[p] > worst) { worst = lst[p]; wpos = p; }
          }
        }
      }
      __syncthreads();
    }
    u64* cb = cand + ((size_t)(b * M_ + qt * 64 + sq) * S + s) * 16;
    for (int r = 0; r < K_; ++r) {
      u64 mn = lst[0];
#pragma unroll
      for (int p = 1; p < 16; ++p)
        if (lst[p] < mn) mn = lst[p];
      u64 m2 = mn;
#pragma unroll
      for (int off = 1; off < 8; off <<= 1) {
        const u64 o = __shfl_xor(m2, off, 64);
        if (o < m2) m2 = o;
      }
      if (mn == m2) {
        bool done = false;
#pragma unroll
        for (int p = 0; p < 16; ++p)
          if (!done && lst[p] == m2) { lst[p] = ~0ull; done = true; }
      }
      if (ssub == 0) cb[r] = m2;
    }
  }
}

// Tile-based (R8-proven, ~53us): 256 merge/gather blocks + 16 tail blocks.
__global__ __launch_bounds__(256) void gather_tail_kernel(
    const float* __restrict__ pos, const int* __restrict__ fps_idx,
    const unsigned short* __restrict__ h, const float* __restrict__ ctrl,
    const float* __restrict__ gamma, const float* __restrict__ beta,
    const u64* __restrict__ cand, float* __restrict__ out, int S,
    int batch_as_i64) {
  const int g = blockIdx.x;
  const int t = threadIdx.x;
  const int A = B_ * M_ * COUT_;
  const int P = B_ * M_ * 3;
  if (g >= 256) {  // tail blocks
    const int gid2 = (g - 256) * 256 + t;
    for (int i = 0; i < 16; ++i) {
      const int gid = gid2 + 4096 * i;
      if (gid < P) {
        const int Q = gid / 3;
        const int c = gid - Q * 3;
        const int b = Q >> 10;
        const int idx = fps_idx[Q];
        out[A + gid] = pos[((size_t)b * N_ + idx) * 3 + c];
      } else {
        const int Q = gid - P;
        if (Q < B_ * M_) {
          const int b = Q >> 10;
          float* base = out + A + P;
          if (batch_as_i64)
            ((long long*)base)[Q] = (long long)b;
          else
            base[Q] = (float)b;
        }
      }
    }
    return;
  }
  __shared__ u64 cl[64 * 128];  // 64 queries x (S*16 <= 128)
  __shared__ int nbi[64 * 16];
  __shared__ float scsh[256];
  const int b = g >> 4, qt = g & 15;
  if (t < 128) {
    const float inv = 1.0f / (float)(B_ * N_);
    const float mean = ctrl[t] * inv;
    const float var = ctrl[128 + t] * inv - mean * mean;
    const float r = 1.0f / sqrtf(var + 1e-5f);
    const float sc = gamma[t] * r;
    scsh[t] = sc;
    scsh[128 + t] = beta[t] - mean * sc;
  }
  const int S16 = S * 16;
  const u64* cg = cand + (size_t)(b * M_ + qt * 64) * S16;
  for (int i = t; i < 64 * S16; i += 256) cl[i] = cg[i];
  __syncthreads();
  if (t < 64) {  // exact S-way sorted merge, query t
    int ptr[8] = {0, 0, 0, 0, 0, 0, 0, 0};
    for (int r = 0; r < K_; ++r) {
      u64 mn = ~0ull;
      int ms = 0;
      for (int s = 0; s < S; ++s) {
        if (ptr[s] < 16) {
          const u64 v = cl[t * S16 + s * 16 + ptr[s]];
          if (v < mn) { mn = v; ms = s; }
        }
      }
      nbi[t * 16 + r] = (int)(unsigned)(mn & 0xFFFFFFFFu);
      ptr[ms]++;
    }
  }
  __syncthreads();
  // gather: 4 lanes/query x 32 channels; min+max so BN sign is safe post-pool
  const int q = t >> 2;
  const int c0 = (t & 3) * 32;
  float mx[32], mn[32];
#pragma unroll
  for (int i = 0; i < 32; ++i) { mx[i] = -3.402823466e38f; mn[i] = 3.402823466e38f; }
#pragma unroll
  for (int k = 0; k < K_; ++k) {
    const int n = nbi[q * 16 + k];
    const uint4* hr = (const uint4*)(h + ((size_t)b * N_ + n) * COUT_ + c0);
#pragma unroll
    for (int j = 0; j < 4; ++j) {
      const uint4 hv = hr[j];
      const unsigned hu[4] = {hv.x, hv.y, hv.z, hv.w};
#pragma unroll
      for (int i = 0; i < 4; ++i) {
        const float lo = __uint_as_float(hu[i] << 16);
        const float hi = __uint_as_float(hu[i] & 0xFFFF0000u);
        const int c = j * 8 + 2 * i;
        mx[c] = fmaxf(mx[c], lo); mn[c] = fminf(mn[c], lo);
        mx[c + 1] = fmaxf(mx[c + 1], hi); mn[c + 1] = fminf(mn[c + 1], hi);
      }
    }
  }
  float* ob = out + (size_t)(b * M_ + qt * 64 + q) * COUT_ + c0;
#pragma unroll
  for (int i = 0; i < 8; ++i) {
    float4 o;
#pragma unroll
    for (int e = 0; e < 4; ++e) {
      const int c = 4 * i + e;
      const float sc = scsh[c0 + c], sh = scsh[128 + c0 + c];
      const float v = sc >= 0.f ? mx[c] : mn[c];
      (&o.x)[e] = fmaf(v, sc, sh);
    }
    *(float4*)(ob + 4 * i) = o;
  }
}

extern "C" void kernel_launch(void* const* d_in, const int* in_sizes, int n_in,
                              void* d_out, int out_size, void* d_ws, size_t ws_size,
                              hipStream_t stream) {
  const float* features = (const float*)d_in[0];
  const float* positions = (const float*)d_in[1];
  const float* W = (const float*)d_in[3];
  const float* bias = (const float*)d_in[4];
  const float* gamma = (const float*)d_in[5];
  const float* beta = (const float*)d_in[6];
  float* out = (float*)d_out;
  unsigned char* ws = (unsigned char*)d_ws;

  int* fps_idx = (int*)ws;                            // 64 KB
  unsigned short* h = (unsigned short*)(ws + 65536);  // bf16, 16.8 MB
  const size_t hoff = 65536 + (size_t)B_ * N_ * COUT_ * 2;
  float* ctrl = (float*)(ws + hoff);                  // 4 KB
  u64* cand = (u64*)(ws + hoff + 4096);
  const size_t base = hoff + 4096;

  int S = 8;
  while (S > 1 && base + (size_t)B_ * M_ * S * 16 * 8 > ws_size) S >>= 1;

  const int rem = out_size - (B_ * M_ * COUT_) - (B_ * M_ * 3);
  const int batch_as_i64 = (rem >= 2 * B_ * M_) ? 1 : 0;

  hipMemsetAsync(ctrl, 0, 4096, stream);
  mega_kernel<<<B_ + 512 + 256 * S, 512, 0, stream>>>(
      positions, features, W, bias, fps_idx, h, ctrl, cand, S);
  gather_tail_kernel<<<256 + 16, 256, 0, stream>>>(
      positions, fps_idx, h, ctrl, gamma, beta, cand, out, S, batch_as_i64);
}